// Round 12
// baseline (113.276 us; speedup 1.0000x reference)
//
#include <hip/hip_runtime.h>

#define NPTS 8192      // H*W
#define BCLS 4         // C
#define NP   6         // B*(C-1) pairs
#define R2   9.0f
#define RAD  3.0f
#define GRD  64
#define NCELL (GRD*GRD)
#define PCAP 2048      // pending-list capacity (overflow -> sweep fallback)
#define LDSK 2048      // LDS kept-center accumulator cap (overflow -> global)
#define WSER 128       // wave-serial tail threshold (<= 2 per lane)

#define ST_U 0u
#define ST_A 1u
#define ST_D 2u

// ---------------------------------------------------------------------------
// One block per (batch, class) pair. Grid-space layout (R10/R11): sps[e]
// (coords) + cmb[e] = pixel<<2|status in grid-sorted order => window scans are
// two contiguous LDS streams (cell >= 2*RAD => <= 2x2 cells; row cells merge
// into one flat [s,e) range). Pixel order == candidate order => identical
// comparisons/tie-breaks vs the sequential greedy (same _rn arithmetic).
// Fixed-point engine: R7 pending-list block rounds while pc > WSER; once
// pc <= WSER, wave 0 finishes alone (lane owns <= 2 entries, ballot loop,
// __threadfence_block per iteration: LDS instructions are wave-wide so the
// lgkmcnt(0) fence makes the wave's prior writes visible). Least-pixel pending
// always resolves per iteration => <= pc iterations; capped + requeue into the
// block rounds as an (unreachable) safety net. Rounds beat spin/DFS (R8/R10);
// this removes only the barrier tax on the small-tail rounds.
// ---------------------------------------------------------------------------
__global__ __launch_bounds__(1024) void k_fused(
    const float* __restrict__ seg, const float* __restrict__ lidar,
    float* __restrict__ sumx, float* __restrict__ sumy, float* __restrict__ cntw,
    float* __restrict__ out)
{
    const int p = blockIdx.x;
    const int b = p / 3, cls = p % 3 + 1;
    const int tid = threadIdx.x, lane = tid & 63, wv = tid >> 6;
    const int base = p * NPTS;

    __shared__ float2 sps[NPTS];                // 64 KB: pixel-space, then grid-space
    __shared__ unsigned int cmb[NPTS];          // 32 KB: pixel<<2 | status (grid)
    __shared__ unsigned int cellpack[NCELL];    // 16 KB: start<<16 | cnt
    __shared__ unsigned short plist[2][PCAP];   //  8 KB: pending lists
    __shared__ float ksx[LDSK], ksy[LDSK], kcn[LDSK];  // 24 KB
    __shared__ int pcnt[2];
    __shared__ unsigned long long ballots[128]; //  1 KB: mask words, later kept words
    __shared__ unsigned int base128[128];       // 512 B
    __shared__ unsigned int wtot[16];
    __shared__ float redbuf[4][16];
    __shared__ float sbminx, sbminy, scell;
    __shared__ int sM, sK;

    float* ok = out + (size_t)2 * NP * NPTS + base;

    // ---- P0: zeroing ----
    for (int k = tid; k < NPTS; k += 1024) { cmb[k] = ST_U; ok[k] = 0.f; }
    {
        float2* oc = (float2*)(out + (size_t)2 * base);
        for (int k = tid; k < NPTS; k += 1024) oc[k] = make_float2(0.f, 0.f);
    }
    for (int k = tid; k < NCELL; k += 1024) cellpack[k] = 0u;
    for (int k = tid; k < LDSK; k += 1024) { ksx[k] = 0.f; ksy[k] = 0.f; kcn[k] = 0.f; }
    if (tid == 0) { pcnt[0] = 0; pcnt[1] = 0; }

    // ---- P1: argmax -> mask ballots; stage lidar into sps (pixel space) ----
    const float* segb = seg + (size_t)b * BCLS * NPTS;
    const float* lx = lidar + (size_t)b * 2 * NPTS;
    const float* ly = lx + NPTS;
    for (int c0 = 0; c0 < 8; ++c0) {
        int n = c0 * 1024 + tid;
        float bv = segb[n];
        int bc = 0;
        #pragma unroll
        for (int c2 = 1; c2 < BCLS; ++c2) {
            float v = segb[c2 * NPTS + n];
            if (v > bv) { bv = v; bc = c2; }   // strict >: first index wins ties
        }
        unsigned long long bal = __ballot(bc == cls);
        if (lane == 0) ballots[c0 * 16 + wv] = bal;
    }
    for (int n = tid; n < NPTS; n += 1024) sps[n] = make_float2(lx[n], ly[n]);
    __syncthreads();
    if (wv == 0) {                              // M = sum of popcounts
        unsigned int s = (unsigned int)__popcll(ballots[2 * lane]) +
                         (unsigned int)__popcll(ballots[2 * lane + 1]);
        for (int d = 1; d < 64; d <<= 1) s += __shfl_xor(s, d, 64);
        if (lane == 0) sM = (int)s;
    }

    // ---- P2: bbox (chunked: thread owns pixels tid*8..tid*8+7) ----
    const unsigned long long mw = ballots[tid >> 3];
    {
        float mnx = 3e38f, mxx = -3e38f, mny = 3e38f, mxy = -3e38f;
        #pragma unroll
        for (int q = 0; q < 8; ++q) {
            int n = tid * 8 + q;
            bool m = (mw >> (((tid & 7) << 3) + q)) & 1ull;
            float2 c = sps[n];
            if (m) {
                mnx = fminf(mnx, c.x); mxx = fmaxf(mxx, c.x);
                mny = fminf(mny, c.y); mxy = fmaxf(mxy, c.y);
            }
        }
        for (int d = 32; d; d >>= 1) {
            mnx = fminf(mnx, __shfl_xor(mnx, d, 64));
            mxx = fmaxf(mxx, __shfl_xor(mxx, d, 64));
            mny = fminf(mny, __shfl_xor(mny, d, 64));
            mxy = fmaxf(mxy, __shfl_xor(mxy, d, 64));
        }
        if (lane == 0) { redbuf[0][wv] = mnx; redbuf[1][wv] = mxx;
                         redbuf[2][wv] = mny; redbuf[3][wv] = mxy; }
    }
    __syncthreads();
    if (tid == 0) {
        float a = redbuf[0][0], b2 = redbuf[1][0], c = redbuf[2][0], d = redbuf[3][0];
        for (int q = 1; q < 16; ++q) {
            a = fminf(a, redbuf[0][q]); b2 = fmaxf(b2, redbuf[1][q]);
            c = fminf(c, redbuf[2][q]); d = fmaxf(d, redbuf[3][q]);
        }
        sbminx = a; sbminy = c;
        scell = fmaxf(2.0f * RAD, fmaxf(b2 - a, d - c) / 63.0f);
    }
    __syncthreads();
    const float bminx = sbminx, bminy = sbminy, inv = 1.0f / scell;
    const int M = sM;

    // ---- P3: grid count / scan / scatter; coords held in regs across scatter ----
    float xq[8], yq[8];
    int cellq[8];
    #pragma unroll
    for (int q = 0; q < 8; ++q) {
        int n = tid * 8 + q;
        bool m = (mw >> (((tid & 7) << 3) + q)) & 1ull;
        float2 c = sps[n];
        xq[q] = c.x; yq[q] = c.y;
        int ix = min(GRD - 1, max(0, (int)((c.x - bminx) * inv)));
        int iy = min(GRD - 1, max(0, (int)((c.y - bminy) * inv)));
        cellq[q] = m ? (iy * GRD + ix) : -1;
        if (m) atomicAdd(&cellpack[iy * GRD + ix], 1u);
    }
    __syncthreads();
    {
        unsigned int c4[4], t4 = 0;
        #pragma unroll
        for (int q = 0; q < 4; ++q) { c4[q] = cellpack[tid * 4 + q]; t4 += c4[q]; }
        unsigned int v = t4;
        for (int d = 1; d < 64; d <<= 1) {
            unsigned int u = __shfl_up(v, d, 64);
            if (lane >= d) v += u;
        }
        if (lane == 63) wtot[wv] = v;
        __syncthreads();
        if (tid == 0) {
            unsigned int acc = 0;
            for (int q = 0; q < 16; ++q) { unsigned int t = wtot[q]; wtot[q] = acc; acc += t; }
        }
        __syncthreads();
        unsigned int excl = wtot[wv] + v - t4;
        #pragma unroll
        for (int q = 0; q < 4; ++q) { cellpack[tid * 4 + q] = excl << 16; excl += c4[q]; }
    }
    __syncthreads();
    #pragma unroll
    for (int q = 0; q < 8; ++q) {
        if (cellq[q] >= 0) {
            unsigned int old = atomicAdd(&cellpack[cellq[q]], 1u);
            unsigned int pos = (old >> 16) + (old & 0xffffu);
            sps[pos] = make_float2(xq[q], yq[q]);
            cmb[pos] = ((unsigned int)(tid * 8 + q) << 2) | ST_U;
        }
    }   // cellpack now = start<<16 | cnt; sps/cmb now grid-space
    __syncthreads();

    // flat window row scan over two contiguous streams (branchless)
    #define ROW_FLAGS(CY, CX0, CX1, NI, ME, DEAD, UNDEC)                          \
    {                                                                             \
        unsigned int wa = cellpack[(CY) * GRD + (CX0)];                           \
        unsigned int wb = cellpack[(CY) * GRD + (CX1)];                           \
        unsigned int f0 = wa >> 16, f1 = (wb >> 16) + (wb & 0xffffu);             \
        for (unsigned int f = f0; f < f1; ++f) {                                  \
            unsigned int wf = cmb[f];                                             \
            float2 q = sps[f];                                                    \
            float dx = __fsub_rn((ME).x, q.x), dy = __fsub_rn((ME).y, q.y);       \
            float d2 = __fadd_rn(__fmul_rn(dx, dx), __fmul_rn(dy, dy));           \
            bool in = (d2 < R2) & ((int)(wf >> 2) < (NI));                        \
            DEAD  |= in & ((wf & 3u) == ST_A);                                    \
            UNDEC |= in & ((wf & 3u) == ST_U);                                    \
        }                                                                         \
    }
    #define SCAN_FLAGS(NI, ME, DEAD, UNDEC)                                       \
    {                                                                             \
        int cx0 = max(0, (int)(((ME).x - RAD - bminx) * inv));                    \
        int cx1 = min(GRD - 1, (int)(((ME).x + RAD - bminx) * inv));              \
        int cy0 = max(0, (int)(((ME).y - RAD - bminy) * inv));                    \
        int cy1 = min(GRD - 1, (int)(((ME).y + RAD - bminy) * inv));              \
        DEAD = false; UNDEC = false;                                              \
        ROW_FLAGS(cy0, cx0, cx1, NI, ME, DEAD, UNDEC);                            \
        if (cy1 > cy0) ROW_FLAGS(cy1, cx0, cx1, NI, ME, DEAD, UNDEC);             \
    }

    // ---- P4 round 0: full sweep (grid order), wave-ordered pending append ----
    for (int e = tid; e < M; e += 1024) {
        unsigned int w = cmb[e];
        int ni = (int)(w >> 2);
        float2 me = sps[e];
        bool dead, undec;
        SCAN_FLAGS(ni, me, dead, undec);
        if (dead) cmb[e] = (w & ~3u) | ST_D;
        else if (!undec) cmb[e] = (w & ~3u) | ST_A;
        bool pendf = !dead && undec;
        unsigned long long act = __ballot(true);
        unsigned long long bal = __ballot(pendf);
        int leader = __builtin_ctzll(act);
        int cnt = __popcll(bal);
        int wbase = 0;
        if (lane == leader && cnt) wbase = atomicAdd(&pcnt[0], cnt);
        wbase = __shfl(wbase, leader, 64);
        if (pendf) {
            int pos = wbase + __popcll(bal & ((1ull << lane) - 1ull));
            if (pos < PCAP) plist[0][pos] = (unsigned short)e;
        }
    }

    // ---- P4 rounds: block rounds while big, wave-serial tail when small ----
    int cur = 0;
    for (int round = 0; round < NPTS; ++round) {
        __syncthreads();
        int pc = pcnt[cur];
        if (pc == 0) break;
        if (tid == 0) pcnt[cur ^ 1] = 0;
        if (pc <= WSER) {
            // wave 0 finishes alone; others proceed to the top barrier.
            if (wv == 0) {
                int e0 = (lane < pc) ? plist[cur][lane] : -1;
                int e1 = (lane + 64 < pc) ? plist[cur][lane + 64] : -1;
                int ni0 = 0, ni1 = 0;
                float2 me0 = make_float2(0.f, 0.f), me1 = me0;
                if (e0 >= 0) { unsigned int w = cmb[e0]; ni0 = (int)(w >> 2); me0 = sps[e0]; }
                if (e1 >= 0) { unsigned int w = cmb[e1]; ni1 = (int)(w >> 2); me1 = sps[e1]; }
                bool d0 = (e0 < 0), d1 = (e1 < 0);
                int iter = 0;
                while (__ballot((!d0) | (!d1)) != 0ull && iter < 512) {
                    __threadfence_block();       // wave-wide LDS writes visible
                    if (!d0) {
                        bool dead, undec;
                        SCAN_FLAGS(ni0, me0, dead, undec);
                        if (dead)        { cmb[e0] = ((unsigned int)ni0 << 2) | ST_D; d0 = true; }
                        else if (!undec) { cmb[e0] = ((unsigned int)ni0 << 2) | ST_A; d0 = true; }
                    }
                    if (!d1) {
                        bool dead, undec;
                        SCAN_FLAGS(ni1, me1, dead, undec);
                        if (dead)        { cmb[e1] = ((unsigned int)ni1 << 2) | ST_D; d1 = true; }
                        else if (!undec) { cmb[e1] = ((unsigned int)ni1 << 2) | ST_A; d1 = true; }
                    }
                    ++iter;
                }
                // safety requeue (unreachable: <= pc iterations suffice)
                unsigned long long l0 = __ballot(!d0), l1 = __ballot(!d1);
                if ((l0 | l1) != 0ull) {
                    __threadfence_block();
                    int cnt = __popcll(l0) + __popcll(l1);
                    int wbase = 0;
                    if (lane == 0) wbase = atomicAdd(&pcnt[cur ^ 1], cnt);
                    wbase = __shfl(wbase, 0, 64);
                    int r0 = __popcll(l0 & ((1ull << lane) - 1ull));
                    if (!d0) plist[cur ^ 1][wbase + r0] = (unsigned short)e0;
                    int off1 = __popcll(l0) + __popcll(l1 & ((1ull << lane) - 1ull));
                    if (!d1) plist[cur ^ 1][wbase + off1] = (unsigned short)e1;
                }
            }
            cur ^= 1;
            continue;                            // top barrier syncs everyone
        }
        __syncthreads();                         // protect pcnt reset (big path)
        if (pc > PCAP) {                         // overflow fallback: full sweeps
            for (;;) {
                bool any = false;
                __syncthreads();
                for (int e = tid; e < M; e += 1024) {
                    unsigned int w = cmb[e];
                    if ((w & 3u) != ST_U) continue;
                    int ni = (int)(w >> 2);
                    float2 me = sps[e];
                    bool dead, undec;
                    SCAN_FLAGS(ni, me, dead, undec);
                    if (dead) cmb[e] = (w & ~3u) | ST_D;
                    else if (!undec) cmb[e] = (w & ~3u) | ST_A;
                    else any = true;
                }
                if (__syncthreads_count(any) == 0) break;
            }
            break;
        }
        for (int idx = tid; idx < pc; idx += 1024) {
            int e = plist[cur][idx];
            unsigned int w = cmb[e];
            int ni = (int)(w >> 2);
            float2 me = sps[e];
            bool dead, undec;
            SCAN_FLAGS(ni, me, dead, undec);
            if (dead) cmb[e] = (w & ~3u) | ST_D;
            else if (!undec) cmb[e] = (w & ~3u) | ST_A;
            bool pendf = !dead && undec;
            unsigned long long act = __ballot(true);
            unsigned long long bal = __ballot(pendf);
            int leader = __builtin_ctzll(act);
            int cnt = __popcll(bal);
            int wbase = 0;
            if (lane == leader && cnt) wbase = atomicAdd(&pcnt[cur ^ 1], cnt);
            wbase = __shfl(wbase, leader, 64);
            if (pendf) {
                int pos = wbase + __popcll(bal & ((1ull << lane) - 1ull));
                if (pos < PCAP) plist[cur ^ 1][pos] = (unsigned short)e;
            }
        }
        cur ^= 1;
    }
    __syncthreads();

    // ---- kept-rank over grid space: ballot bitmask + wave-scanned prefix ----
    for (int k = 0; k < 8; ++k) {
        int e = (k << 10) + tid;
        unsigned long long bal = __ballot((cmb[e] & 3u) == ST_A);  // e>=M stays U
        if (lane == 0) ballots[(k << 4) + wv] = bal;
    }
    __syncthreads();
    if (wv == 0) {
        unsigned int p0 = (unsigned int)__popcll(ballots[2 * lane]);
        unsigned int p1 = (unsigned int)__popcll(ballots[2 * lane + 1]);
        unsigned int s = p0 + p1, v = s;
        for (int d = 1; d < 64; d <<= 1) {
            unsigned int u = __shfl_up(v, d, 64);
            if (lane >= d) v += u;
        }
        base128[2 * lane] = v - s;
        base128[2 * lane + 1] = v - p1;
        if (lane == 63) sK = (int)v;
    }
    __syncthreads();
    #define KRANK(E) ((int)base128[(E) >> 6] +                                    \
                      __popcll(ballots[(E) >> 6] & ((1ull << ((E) & 63)) - 1ull)))
    if (sK > LDSK) {                            // cold fallback prep: zero globals
        for (int k = tid; k < NPTS; k += 1024) {
            sumx[base + k] = 0.f; sumy[base + k] = 0.f; cntw[base + k] = 0.f;
        }
        __syncthreads();
    }

    // ---- P5: assignment + LDS accumulation (contiguous branchless argmin) ----
    #define ROW_ARGMIN(CY, CX0, CX1, ME, BD, BE, BN)                              \
    {                                                                             \
        unsigned int wa = cellpack[(CY) * GRD + (CX0)];                           \
        unsigned int wb = cellpack[(CY) * GRD + (CX1)];                           \
        unsigned int f0 = wa >> 16, f1 = (wb >> 16) + (wb & 0xffffu);             \
        for (unsigned int f = f0; f < f1; ++f) {                                  \
            unsigned int wf = cmb[f];                                             \
            float2 q = sps[f];                                                    \
            float dx = __fsub_rn((ME).x, q.x), dy = __fsub_rn((ME).y, q.y);       \
            float d2 = __fadd_rn(__fmul_rn(dx, dx), __fmul_rn(dy, dy));           \
            int nf = (int)(wf >> 2);                                              \
            bool better = ((wf & 3u) == ST_A) &                                   \
                          ((d2 < BD) | ((d2 == BD) & (nf < BN)));                 \
            BD = better ? d2 : BD;                                                \
            BE = better ? (int)f : BE;                                            \
            BN = better ? nf : BN;                                                \
        }                                                                         \
    }
    for (int e = tid; e < M; e += 1024) {
        unsigned int w = cmb[e];
        float2 me = sps[e];
        int be;
        if ((w & 3u) == ST_A) {
            be = e;                              // self: unique d2 = 0
        } else {
            int cx0 = max(0, (int)((me.x - RAD - bminx) * inv));
            int cx1 = min(GRD - 1, (int)((me.x + RAD - bminx) * inv));
            int cy0 = max(0, (int)((me.y - RAD - bminy) * inv));
            int cy1 = min(GRD - 1, (int)((me.y + RAD - bminy) * inv));
            float bd = 3e38f;
            be = -1;
            int bn = 1 << 30;
            ROW_ARGMIN(cy0, cx0, cx1, me, bd, be, bn);
            if (cy1 > cy0) ROW_ARGMIN(cy1, cx0, cx1, me, bd, be, bn);
            if (be < 0) continue;                // impossible when M > 0
        }
        int r = KRANK(be);
        if (r < LDSK) {
            atomicAdd(&ksx[r], me.x);
            atomicAdd(&ksy[r], me.y);
            atomicAdd(&kcn[r], 1.0f);
        } else {                                 // cold fallback: global by grid pos
            atomicAdd(&sumx[base + be], me.x);
            atomicAdd(&sumy[base + be], me.y);
            atomicAdd(&cntw[base + be], 1.0f);
        }
    }
    __syncthreads();

    // ---- P6: kept candidates overwrite the zeroed output slice ----
    for (int e = tid; e < M; e += 1024) {
        unsigned int w = cmb[e];
        if ((w & 3u) != ST_A) continue;
        int n = (int)(w >> 2);
        int r = KRANK(e);
        float sx, sy, c;
        if (r < LDSK) { sx = ksx[r]; sy = ksy[r]; c = kcn[r]; }
        else { sx = sumx[base + e]; sy = sumy[base + e]; c = cntw[base + e]; }
        out[2 * (base + n)]     = sx / c;        // c >= 1 (self-assign)
        out[2 * (base + n) + 1] = sy / c;
        ok[n] = 1.0f;
    }
}

// ---------------------------------------------------------------------------
extern "C" void kernel_launch(void* const* d_in, const int* in_sizes, int n_in,
                              void* d_out, int out_size, void* d_ws, size_t ws_size,
                              hipStream_t stream) {
    const float* seg   = (const float*)d_in[0];   // [B,C,H,W] f32
    const float* lidar = (const float*)d_in[1];   // [B,2,H,W] f32
    float* out = (float*)d_out;

    const size_t A = (size_t)NP * NPTS;           // 49152
    float* sumx = (float*)d_ws;                   // 4A (fallback only)
    float* sumy = sumx + A;                       // 4A
    float* cntw = sumy + A;                       // 4A

    k_fused<<<NP, 1024, 0, stream>>>(seg, lidar, sumx, sumy, cntw, out);
}

// Round 13
// 109.326 us; speedup vs baseline: 1.0361x; 1.0361x over previous
//
#include <hip/hip_runtime.h>

#define NPTS 8192      // H*W
#define BCLS 4         // C
#define NP   6         // B*(C-1) pairs
#define R2   9.0f
#define RAD  3.0f
#define GRD  64
#define NCELL (GRD*GRD)
#define PCAP 2048      // pending-list capacity (overflow -> sweep fallback)
#define LDSK 2048      // LDS kept-center accumulator cap (overflow -> global)

#define ST_U 0u
#define ST_A 1u
#define ST_D 2u

// ---------------------------------------------------------------------------
// One block per (batch, class) pair. Grid-space layout (R10/R11): sps[e]
// (coords) + cmb[e] = pixel<<2|status in grid-sorted order => window scans are
// two contiguous LDS streams (cell >= 2*RAD => <= 2x2 cells; row cells merge
// into one flat [s,e) range). Pixel order == candidate order => identical
// comparisons/tie-breaks vs the sequential greedy (same _rn arithmetic).
// Fixed-point engine (R13): R11's all-waves pending-list block rounds with
// (a) per-round counters pcnt2[] -> ONE barrier per round (no reset barrier),
// (b) intra-wave chain collapse: an undecided entry re-scans inside the wave
//     (fence + progress-ballot, exit on stall); grid-ordered pending => most
//     chains are wave-local and resolve without a block round.
// Engine scoreboard: block rounds 58us < wave-serial 63 (R12) < spin 74 (R8)
// < DFS 79 (R10) -- schemes serializing work into per-lane latency chains
// lose; this keeps all 16 waves collectively scanning. Monotone U->{A,D}
// word-granular writes => stale reads only delay, never corrupt.
// ---------------------------------------------------------------------------
__global__ __launch_bounds__(1024) void k_fused(
    const float* __restrict__ seg, const float* __restrict__ lidar,
    float* __restrict__ sumx, float* __restrict__ sumy, float* __restrict__ cntw,
    float* __restrict__ out)
{
    const int p = blockIdx.x;
    const int b = p / 3, cls = p % 3 + 1;
    const int tid = threadIdx.x, lane = tid & 63, wv = tid >> 6;
    const int base = p * NPTS;

    __shared__ float2 sps[NPTS];                // 64 KB: pixel-space, then grid-space
    __shared__ unsigned int cmb[NPTS];          // 32 KB: pixel<<2 | status (grid)
    __shared__ unsigned int cellpack[NCELL];    // 16 KB: start<<16 | cnt
    __shared__ unsigned short plist[2][PCAP];   //  8 KB: pending lists
    __shared__ float ksx[LDSK], ksy[LDSK], kcn[LDSK];  // 24 KB
    __shared__ int pcnt2[64];                   // 256 B: per-round counters
    __shared__ unsigned long long ballots[128]; //  1 KB: mask words, later kept words
    __shared__ unsigned int base128[128];       // 512 B
    __shared__ unsigned int wtot[16];
    __shared__ float redbuf[4][16];
    __shared__ float sbminx, sbminy, scell;
    __shared__ int sM, sK;

    float* ok = out + (size_t)2 * NP * NPTS + base;

    // ---- P0: zeroing ----
    for (int k = tid; k < NPTS; k += 1024) { cmb[k] = ST_U; ok[k] = 0.f; }
    {
        float2* oc = (float2*)(out + (size_t)2 * base);
        for (int k = tid; k < NPTS; k += 1024) oc[k] = make_float2(0.f, 0.f);
    }
    for (int k = tid; k < NCELL; k += 1024) cellpack[k] = 0u;
    for (int k = tid; k < LDSK; k += 1024) { ksx[k] = 0.f; ksy[k] = 0.f; kcn[k] = 0.f; }
    if (tid < 64) pcnt2[tid] = 0;

    // ---- P1: argmax -> mask ballots; stage lidar into sps (pixel space) ----
    const float* segb = seg + (size_t)b * BCLS * NPTS;
    const float* lx = lidar + (size_t)b * 2 * NPTS;
    const float* ly = lx + NPTS;
    for (int c0 = 0; c0 < 8; ++c0) {
        int n = c0 * 1024 + tid;
        float bv = segb[n];
        int bc = 0;
        #pragma unroll
        for (int c2 = 1; c2 < BCLS; ++c2) {
            float v = segb[c2 * NPTS + n];
            if (v > bv) { bv = v; bc = c2; }   // strict >: first index wins ties
        }
        unsigned long long bal = __ballot(bc == cls);
        if (lane == 0) ballots[c0 * 16 + wv] = bal;
    }
    for (int n = tid; n < NPTS; n += 1024) sps[n] = make_float2(lx[n], ly[n]);
    __syncthreads();
    if (wv == 0) {                              // M = sum of popcounts
        unsigned int s = (unsigned int)__popcll(ballots[2 * lane]) +
                         (unsigned int)__popcll(ballots[2 * lane + 1]);
        for (int d = 1; d < 64; d <<= 1) s += __shfl_xor(s, d, 64);
        if (lane == 0) sM = (int)s;
    }

    // ---- P2: bbox (chunked: thread owns pixels tid*8..tid*8+7) ----
    const unsigned long long mw = ballots[tid >> 3];
    {
        float mnx = 3e38f, mxx = -3e38f, mny = 3e38f, mxy = -3e38f;
        #pragma unroll
        for (int q = 0; q < 8; ++q) {
            int n = tid * 8 + q;
            bool m = (mw >> (((tid & 7) << 3) + q)) & 1ull;
            float2 c = sps[n];
            if (m) {
                mnx = fminf(mnx, c.x); mxx = fmaxf(mxx, c.x);
                mny = fminf(mny, c.y); mxy = fmaxf(mxy, c.y);
            }
        }
        for (int d = 32; d; d >>= 1) {
            mnx = fminf(mnx, __shfl_xor(mnx, d, 64));
            mxx = fmaxf(mxx, __shfl_xor(mxx, d, 64));
            mny = fminf(mny, __shfl_xor(mny, d, 64));
            mxy = fmaxf(mxy, __shfl_xor(mxy, d, 64));
        }
        if (lane == 0) { redbuf[0][wv] = mnx; redbuf[1][wv] = mxx;
                         redbuf[2][wv] = mny; redbuf[3][wv] = mxy; }
    }
    __syncthreads();
    if (tid == 0) {
        float a = redbuf[0][0], b2 = redbuf[1][0], c = redbuf[2][0], d = redbuf[3][0];
        for (int q = 1; q < 16; ++q) {
            a = fminf(a, redbuf[0][q]); b2 = fmaxf(b2, redbuf[1][q]);
            c = fminf(c, redbuf[2][q]); d = fmaxf(d, redbuf[3][q]);
        }
        sbminx = a; sbminy = c;
        scell = fmaxf(2.0f * RAD, fmaxf(b2 - a, d - c) / 63.0f);
    }
    __syncthreads();
    const float bminx = sbminx, bminy = sbminy, inv = 1.0f / scell;
    const int M = sM;

    // ---- P3: grid count / scan / scatter; coords held in regs across scatter ----
    float xq[8], yq[8];
    int cellq[8];
    #pragma unroll
    for (int q = 0; q < 8; ++q) {
        int n = tid * 8 + q;
        bool m = (mw >> (((tid & 7) << 3) + q)) & 1ull;
        float2 c = sps[n];
        xq[q] = c.x; yq[q] = c.y;
        int ix = min(GRD - 1, max(0, (int)((c.x - bminx) * inv)));
        int iy = min(GRD - 1, max(0, (int)((c.y - bminy) * inv)));
        cellq[q] = m ? (iy * GRD + ix) : -1;
        if (m) atomicAdd(&cellpack[iy * GRD + ix], 1u);
    }
    __syncthreads();
    {
        unsigned int c4[4], t4 = 0;
        #pragma unroll
        for (int q = 0; q < 4; ++q) { c4[q] = cellpack[tid * 4 + q]; t4 += c4[q]; }
        unsigned int v = t4;
        for (int d = 1; d < 64; d <<= 1) {
            unsigned int u = __shfl_up(v, d, 64);
            if (lane >= d) v += u;
        }
        if (lane == 63) wtot[wv] = v;
        __syncthreads();
        if (tid == 0) {
            unsigned int acc = 0;
            for (int q = 0; q < 16; ++q) { unsigned int t = wtot[q]; wtot[q] = acc; acc += t; }
        }
        __syncthreads();
        unsigned int excl = wtot[wv] + v - t4;
        #pragma unroll
        for (int q = 0; q < 4; ++q) { cellpack[tid * 4 + q] = excl << 16; excl += c4[q]; }
    }
    __syncthreads();
    #pragma unroll
    for (int q = 0; q < 8; ++q) {
        if (cellq[q] >= 0) {
            unsigned int old = atomicAdd(&cellpack[cellq[q]], 1u);
            unsigned int pos = (old >> 16) + (old & 0xffffu);
            sps[pos] = make_float2(xq[q], yq[q]);
            cmb[pos] = ((unsigned int)(tid * 8 + q) << 2) | ST_U;
        }
    }   // cellpack now = start<<16 | cnt; sps/cmb now grid-space
    __syncthreads();

    // flat window row scan over two contiguous streams (branchless)
    #define ROW_FLAGS(CY, CX0, CX1, NI, ME, DEAD, UNDEC)                          \
    {                                                                             \
        unsigned int wa = cellpack[(CY) * GRD + (CX0)];                           \
        unsigned int wb = cellpack[(CY) * GRD + (CX1)];                           \
        unsigned int f0 = wa >> 16, f1 = (wb >> 16) + (wb & 0xffffu);             \
        for (unsigned int f = f0; f < f1; ++f) {                                  \
            unsigned int wf = cmb[f];                                             \
            float2 q = sps[f];                                                    \
            float dx = __fsub_rn((ME).x, q.x), dy = __fsub_rn((ME).y, q.y);       \
            float d2 = __fadd_rn(__fmul_rn(dx, dx), __fmul_rn(dy, dy));           \
            bool in = (d2 < R2) & ((int)(wf >> 2) < (NI));                        \
            DEAD  |= in & ((wf & 3u) == ST_A);                                    \
            UNDEC |= in & ((wf & 3u) == ST_U);                                    \
        }                                                                         \
    }
    #define SCAN_FLAGS(NI, ME, DEAD, UNDEC)                                       \
    {                                                                             \
        int cx0 = max(0, (int)(((ME).x - RAD - bminx) * inv));                    \
        int cx1 = min(GRD - 1, (int)(((ME).x + RAD - bminx) * inv));              \
        int cy0 = max(0, (int)(((ME).y - RAD - bminy) * inv));                    \
        int cy1 = min(GRD - 1, (int)(((ME).y + RAD - bminy) * inv));              \
        DEAD = false; UNDEC = false;                                              \
        ROW_FLAGS(cy0, cx0, cx1, NI, ME, DEAD, UNDEC);                            \
        if (cy1 > cy0) ROW_FLAGS(cy1, cx0, cx1, NI, ME, DEAD, UNDEC);             \
    }

    // ---- P4 round 0: full sweep (grid order), wave-ordered pending append ----
    for (int e = tid; e < M; e += 1024) {
        unsigned int w = cmb[e];
        int ni = (int)(w >> 2);
        float2 me = sps[e];
        bool dead, undec;
        SCAN_FLAGS(ni, me, dead, undec);
        if (dead) cmb[e] = (w & ~3u) | ST_D;
        else if (!undec) cmb[e] = (w & ~3u) | ST_A;
        bool pendf = !dead && undec;
        unsigned long long act = __ballot(true);
        unsigned long long bal = __ballot(pendf);
        int leader = __builtin_ctzll(act);
        int cnt = __popcll(bal);
        int wbase = 0;
        if (lane == leader && cnt) wbase = atomicAdd(&pcnt2[0], cnt);
        wbase = __shfl(wbase, leader, 64);
        if (pendf) {
            int pos = wbase + __popcll(bal & ((1ull << lane) - 1ull));
            if (pos < PCAP) plist[0][pos] = (unsigned short)e;
        }
    }

    // ---- P4 rounds: ONE barrier each; intra-wave chain collapse ----
    for (int round = 0; ; ++round) {
        __syncthreads();                         // publishes prev round's list+cnt
        int pc = pcnt2[round];
        if (pc == 0) break;
        int cur = round & 1;
        if (pc > PCAP || round >= 62) {          // overflow / cap: sweep fallback
            for (;;) {
                bool any = false;
                __syncthreads();
                for (int e = tid; e < M; e += 1024) {
                    unsigned int w = cmb[e];
                    if ((w & 3u) != ST_U) continue;
                    int ni = (int)(w >> 2);
                    float2 me = sps[e];
                    bool dead, undec;
                    SCAN_FLAGS(ni, me, dead, undec);
                    if (dead) cmb[e] = (w & ~3u) | ST_D;
                    else if (!undec) cmb[e] = (w & ~3u) | ST_A;
                    else any = true;
                }
                if (__syncthreads_count(any) == 0) break;
            }
            break;
        }
        for (int idx = tid; idx < pc; idx += 1024) {
            int e = plist[cur][idx];
            unsigned int w = cmb[e];
            int ni = (int)(w >> 2);
            float2 me = sps[e];
            bool und = true;
            // intra-wave iterate: grid-ordered pending => chains are wave-local
            for (int it = 0; it < 80; ++it) {
                __threadfence_block();           // wave's prior LDS writes visible
                bool progress = false;
                if (und) {
                    bool dead, undec;
                    SCAN_FLAGS(ni, me, dead, undec);
                    if (dead)        { cmb[e] = (w & ~3u) | ST_D; und = false; progress = true; }
                    else if (!undec) { cmb[e] = (w & ~3u) | ST_A; und = false; progress = true; }
                }
                if (__ballot(progress) == 0ull) break;   // wave stalled: defer
            }
            bool pendf = und;
            unsigned long long act = __ballot(true);
            unsigned long long bal = __ballot(pendf);
            int leader = __builtin_ctzll(act);
            int cnt = __popcll(bal);
            int wbase = 0;
            if (lane == leader && cnt) wbase = atomicAdd(&pcnt2[round + 1], cnt);
            wbase = __shfl(wbase, leader, 64);
            if (pendf) {
                int pos = wbase + __popcll(bal & ((1ull << lane) - 1ull));
                if (pos < PCAP) plist[cur ^ 1][pos] = (unsigned short)e;
            }
        }
    }
    __syncthreads();

    // ---- kept-rank over grid space: ballot bitmask + wave-scanned prefix ----
    for (int k = 0; k < 8; ++k) {
        int e = (k << 10) + tid;
        unsigned long long bal = __ballot((cmb[e] & 3u) == ST_A);  // e>=M stays U
        if (lane == 0) ballots[(k << 4) + wv] = bal;
    }
    __syncthreads();
    if (wv == 0) {
        unsigned int p0 = (unsigned int)__popcll(ballots[2 * lane]);
        unsigned int p1 = (unsigned int)__popcll(ballots[2 * lane + 1]);
        unsigned int s = p0 + p1, v = s;
        for (int d = 1; d < 64; d <<= 1) {
            unsigned int u = __shfl_up(v, d, 64);
            if (lane >= d) v += u;
        }
        base128[2 * lane] = v - s;
        base128[2 * lane + 1] = v - p1;
        if (lane == 63) sK = (int)v;
    }
    __syncthreads();
    #define KRANK(E) ((int)base128[(E) >> 6] +                                    \
                      __popcll(ballots[(E) >> 6] & ((1ull << ((E) & 63)) - 1ull)))
    if (sK > LDSK) {                            // cold fallback prep: zero globals
        for (int k = tid; k < NPTS; k += 1024) {
            sumx[base + k] = 0.f; sumy[base + k] = 0.f; cntw[base + k] = 0.f;
        }
        __syncthreads();
    }

    // ---- P5: assignment + LDS accumulation (contiguous branchless argmin) ----
    #define ROW_ARGMIN(CY, CX0, CX1, ME, BD, BE, BN)                              \
    {                                                                             \
        unsigned int wa = cellpack[(CY) * GRD + (CX0)];                           \
        unsigned int wb = cellpack[(CY) * GRD + (CX1)];                           \
        unsigned int f0 = wa >> 16, f1 = (wb >> 16) + (wb & 0xffffu);             \
        for (unsigned int f = f0; f < f1; ++f) {                                  \
            unsigned int wf = cmb[f];                                             \
            float2 q = sps[f];                                                    \
            float dx = __fsub_rn((ME).x, q.x), dy = __fsub_rn((ME).y, q.y);       \
            float d2 = __fadd_rn(__fmul_rn(dx, dx), __fmul_rn(dy, dy));           \
            int nf = (int)(wf >> 2);                                              \
            bool better = ((wf & 3u) == ST_A) &                                   \
                          ((d2 < BD) | ((d2 == BD) & (nf < BN)));                 \
            BD = better ? d2 : BD;                                                \
            BE = better ? (int)f : BE;                                            \
            BN = better ? nf : BN;                                                \
        }                                                                         \
    }
    for (int e = tid; e < M; e += 1024) {
        unsigned int w = cmb[e];
        float2 me = sps[e];
        int be;
        if ((w & 3u) == ST_A) {
            be = e;                              // self: unique d2 = 0
        } else {
            int cx0 = max(0, (int)((me.x - RAD - bminx) * inv));
            int cx1 = min(GRD - 1, (int)((me.x + RAD - bminx) * inv));
            int cy0 = max(0, (int)((me.y - RAD - bminy) * inv));
            int cy1 = min(GRD - 1, (int)((me.y + RAD - bminy) * inv));
            float bd = 3e38f;
            be = -1;
            int bn = 1 << 30;
            ROW_ARGMIN(cy0, cx0, cx1, me, bd, be, bn);
            if (cy1 > cy0) ROW_ARGMIN(cy1, cx0, cx1, me, bd, be, bn);
            if (be < 0) continue;                // impossible when M > 0
        }
        int r = KRANK(be);
        if (r < LDSK) {
            atomicAdd(&ksx[r], me.x);
            atomicAdd(&ksy[r], me.y);
            atomicAdd(&kcn[r], 1.0f);
        } else {                                 // cold fallback: global by grid pos
            atomicAdd(&sumx[base + be], me.x);
            atomicAdd(&sumy[base + be], me.y);
            atomicAdd(&cntw[base + be], 1.0f);
        }
    }
    __syncthreads();

    // ---- P6: kept candidates overwrite the zeroed output slice ----
    for (int e = tid; e < M; e += 1024) {
        unsigned int w = cmb[e];
        if ((w & 3u) != ST_A) continue;
        int n = (int)(w >> 2);
        int r = KRANK(e);
        float sx, sy, c;
        if (r < LDSK) { sx = ksx[r]; sy = ksy[r]; c = kcn[r]; }
        else { sx = sumx[base + e]; sy = sumy[base + e]; c = cntw[base + e]; }
        out[2 * (base + n)]     = sx / c;        // c >= 1 (self-assign)
        out[2 * (base + n) + 1] = sy / c;
        ok[n] = 1.0f;
    }
}

// ---------------------------------------------------------------------------
extern "C" void kernel_launch(void* const* d_in, const int* in_sizes, int n_in,
                              void* d_out, int out_size, void* d_ws, size_t ws_size,
                              hipStream_t stream) {
    const float* seg   = (const float*)d_in[0];   // [B,C,H,W] f32
    const float* lidar = (const float*)d_in[1];   // [B,2,H,W] f32
    float* out = (float*)d_out;

    const size_t A = (size_t)NP * NPTS;           // 49152
    float* sumx = (float*)d_ws;                   // 4A (fallback only)
    float* sumy = sumx + A;                       // 4A
    float* cntw = sumy + A;                       // 4A

    k_fused<<<NP, 1024, 0, stream>>>(seg, lidar, sumx, sumy, cntw, out);
}

// Round 14
// 107.716 us; speedup vs baseline: 1.0516x; 1.0149x over previous
//
#include <hip/hip_runtime.h>

#define NPTS 8192      // H*W
#define BCLS 4         // C
#define NP   6         // B*(C-1) pairs
#define R2   9.0f
#define RAD  3.0f
#define GRD  64
#define NCELL (GRD*GRD)
#define PCAP 2048      // pending-list capacity (overflow -> sweep fallback)
#define LDSK 2048      // LDS kept-center accumulator cap (overflow -> global)

#define ST_U 0u
#define ST_A 1u
#define ST_D 2u

// ---------------------------------------------------------------------------
// R11 verbatim (best measured: 58.0 us kernel, 108.4 us total).
// One block per (batch, class) pair. Grid-space layout: sps[e] (coords) +
// cmb[e] = pixel<<2|status in grid-sorted order => window scans are two
// contiguous LDS streams (cell >= 2*RAD => window <= 2x2 cells; a row's cells
// merge into one flat [s,e) range). Pixel order == candidate order =>
// comparisons/tie-breaks identical to the sequential greedy (_rn arithmetic,
// strict <). Fixed-point engine: pending-list block rounds (beat wave-serial,
// spin, DFS, and intra-wave-collapse variants by 5-21 us across R8-R13:
// schemes that trade block barriers for per-lane serial latency chains lose).
// Monotone U->{A,D} word-granular writes => stale reads only conservative.
// ---------------------------------------------------------------------------
__global__ __launch_bounds__(1024) void k_fused(
    const float* __restrict__ seg, const float* __restrict__ lidar,
    float* __restrict__ sumx, float* __restrict__ sumy, float* __restrict__ cntw,
    float* __restrict__ out)
{
    const int p = blockIdx.x;
    const int b = p / 3, cls = p % 3 + 1;
    const int tid = threadIdx.x, lane = tid & 63, wv = tid >> 6;
    const int base = p * NPTS;

    __shared__ float2 sps[NPTS];                // 64 KB: pixel-space, then grid-space
    __shared__ unsigned int cmb[NPTS];          // 32 KB: pixel<<2 | status (grid)
    __shared__ unsigned int cellpack[NCELL];    // 16 KB: start<<16 | cnt
    __shared__ unsigned short plist[2][PCAP];   //  8 KB: pending lists
    __shared__ float ksx[LDSK], ksy[LDSK], kcn[LDSK];  // 24 KB
    __shared__ int pcnt[2];
    __shared__ unsigned long long ballots[128]; //  1 KB: mask words, later kept words
    __shared__ unsigned int base128[128];       // 512 B
    __shared__ unsigned int wtot[16];
    __shared__ float redbuf[4][16];
    __shared__ float sbminx, sbminy, scell;
    __shared__ int sM, sK;

    float* ok = out + (size_t)2 * NP * NPTS + base;

    // ---- P0: zeroing ----
    for (int k = tid; k < NPTS; k += 1024) { cmb[k] = ST_U; ok[k] = 0.f; }
    {
        float2* oc = (float2*)(out + (size_t)2 * base);
        for (int k = tid; k < NPTS; k += 1024) oc[k] = make_float2(0.f, 0.f);
    }
    for (int k = tid; k < NCELL; k += 1024) cellpack[k] = 0u;
    for (int k = tid; k < LDSK; k += 1024) { ksx[k] = 0.f; ksy[k] = 0.f; kcn[k] = 0.f; }
    if (tid == 0) { pcnt[0] = 0; pcnt[1] = 0; }

    // ---- P1: argmax -> mask ballots; stage lidar into sps (pixel space) ----
    const float* segb = seg + (size_t)b * BCLS * NPTS;
    const float* lx = lidar + (size_t)b * 2 * NPTS;
    const float* ly = lx + NPTS;
    for (int c0 = 0; c0 < 8; ++c0) {
        int n = c0 * 1024 + tid;
        float bv = segb[n];
        int bc = 0;
        #pragma unroll
        for (int c2 = 1; c2 < BCLS; ++c2) {
            float v = segb[c2 * NPTS + n];
            if (v > bv) { bv = v; bc = c2; }   // strict >: first index wins ties
        }
        unsigned long long bal = __ballot(bc == cls);
        if (lane == 0) ballots[c0 * 16 + wv] = bal;
    }
    for (int n = tid; n < NPTS; n += 1024) sps[n] = make_float2(lx[n], ly[n]);
    __syncthreads();
    if (wv == 0) {                              // M = sum of popcounts
        unsigned int s = (unsigned int)__popcll(ballots[2 * lane]) +
                         (unsigned int)__popcll(ballots[2 * lane + 1]);
        for (int d = 1; d < 64; d <<= 1) s += __shfl_xor(s, d, 64);
        if (lane == 0) sM = (int)s;
    }

    // ---- P2: bbox (chunked: thread owns pixels tid*8..tid*8+7) ----
    const unsigned long long mw = ballots[tid >> 3];
    {
        float mnx = 3e38f, mxx = -3e38f, mny = 3e38f, mxy = -3e38f;
        #pragma unroll
        for (int q = 0; q < 8; ++q) {
            int n = tid * 8 + q;
            bool m = (mw >> (((tid & 7) << 3) + q)) & 1ull;
            float2 c = sps[n];
            if (m) {
                mnx = fminf(mnx, c.x); mxx = fmaxf(mxx, c.x);
                mny = fminf(mny, c.y); mxy = fmaxf(mxy, c.y);
            }
        }
        for (int d = 32; d; d >>= 1) {
            mnx = fminf(mnx, __shfl_xor(mnx, d, 64));
            mxx = fmaxf(mxx, __shfl_xor(mxx, d, 64));
            mny = fminf(mny, __shfl_xor(mny, d, 64));
            mxy = fmaxf(mxy, __shfl_xor(mxy, d, 64));
        }
        if (lane == 0) { redbuf[0][wv] = mnx; redbuf[1][wv] = mxx;
                         redbuf[2][wv] = mny; redbuf[3][wv] = mxy; }
    }
    __syncthreads();
    if (tid == 0) {
        float a = redbuf[0][0], b2 = redbuf[1][0], c = redbuf[2][0], d = redbuf[3][0];
        for (int q = 1; q < 16; ++q) {
            a = fminf(a, redbuf[0][q]); b2 = fmaxf(b2, redbuf[1][q]);
            c = fminf(c, redbuf[2][q]); d = fmaxf(d, redbuf[3][q]);
        }
        sbminx = a; sbminy = c;
        scell = fmaxf(2.0f * RAD, fmaxf(b2 - a, d - c) / 63.0f);
    }
    __syncthreads();
    const float bminx = sbminx, bminy = sbminy, inv = 1.0f / scell;
    const int M = sM;

    // ---- P3: grid count / scan / scatter; coords held in regs across scatter ----
    float xq[8], yq[8];
    int cellq[8];
    #pragma unroll
    for (int q = 0; q < 8; ++q) {
        int n = tid * 8 + q;
        bool m = (mw >> (((tid & 7) << 3) + q)) & 1ull;
        float2 c = sps[n];
        xq[q] = c.x; yq[q] = c.y;
        int ix = min(GRD - 1, max(0, (int)((c.x - bminx) * inv)));
        int iy = min(GRD - 1, max(0, (int)((c.y - bminy) * inv)));
        cellq[q] = m ? (iy * GRD + ix) : -1;
        if (m) atomicAdd(&cellpack[iy * GRD + ix], 1u);
    }
    __syncthreads();
    {
        unsigned int c4[4], t4 = 0;
        #pragma unroll
        for (int q = 0; q < 4; ++q) { c4[q] = cellpack[tid * 4 + q]; t4 += c4[q]; }
        unsigned int v = t4;
        for (int d = 1; d < 64; d <<= 1) {
            unsigned int u = __shfl_up(v, d, 64);
            if (lane >= d) v += u;
        }
        if (lane == 63) wtot[wv] = v;
        __syncthreads();
        if (tid == 0) {
            unsigned int acc = 0;
            for (int q = 0; q < 16; ++q) { unsigned int t = wtot[q]; wtot[q] = acc; acc += t; }
        }
        __syncthreads();
        unsigned int excl = wtot[wv] + v - t4;
        #pragma unroll
        for (int q = 0; q < 4; ++q) { cellpack[tid * 4 + q] = excl << 16; excl += c4[q]; }
    }
    __syncthreads();
    #pragma unroll
    for (int q = 0; q < 8; ++q) {
        if (cellq[q] >= 0) {
            unsigned int old = atomicAdd(&cellpack[cellq[q]], 1u);
            unsigned int pos = (old >> 16) + (old & 0xffffu);
            sps[pos] = make_float2(xq[q], yq[q]);
            cmb[pos] = ((unsigned int)(tid * 8 + q) << 2) | ST_U;
        }
    }   // cellpack now = start<<16 | cnt; sps/cmb now grid-space
    __syncthreads();

    // flat window row scan over two contiguous streams (branchless)
    #define ROW_FLAGS(CY, CX0, CX1, NI, ME, DEAD, UNDEC)                          \
    {                                                                             \
        unsigned int wa = cellpack[(CY) * GRD + (CX0)];                           \
        unsigned int wb = cellpack[(CY) * GRD + (CX1)];                           \
        unsigned int f0 = wa >> 16, f1 = (wb >> 16) + (wb & 0xffffu);             \
        for (unsigned int f = f0; f < f1; ++f) {                                  \
            unsigned int wf = cmb[f];                                             \
            float2 q = sps[f];                                                    \
            float dx = __fsub_rn((ME).x, q.x), dy = __fsub_rn((ME).y, q.y);       \
            float d2 = __fadd_rn(__fmul_rn(dx, dx), __fmul_rn(dy, dy));           \
            bool in = (d2 < R2) & ((int)(wf >> 2) < (NI));                        \
            DEAD  |= in & ((wf & 3u) == ST_A);                                    \
            UNDEC |= in & ((wf & 3u) == ST_U);                                    \
        }                                                                         \
    }
    #define SCAN_FLAGS(NI, ME, DEAD, UNDEC)                                       \
    {                                                                             \
        int cx0 = max(0, (int)(((ME).x - RAD - bminx) * inv));                    \
        int cx1 = min(GRD - 1, (int)(((ME).x + RAD - bminx) * inv));              \
        int cy0 = max(0, (int)(((ME).y - RAD - bminy) * inv));                    \
        int cy1 = min(GRD - 1, (int)(((ME).y + RAD - bminy) * inv));              \
        DEAD = false; UNDEC = false;                                              \
        ROW_FLAGS(cy0, cx0, cx1, NI, ME, DEAD, UNDEC);                            \
        if (cy1 > cy0) ROW_FLAGS(cy1, cx0, cx1, NI, ME, DEAD, UNDEC);             \
    }

    // ---- P4 round 0: full sweep (grid order), wave-ordered pending append ----
    for (int e = tid; e < M; e += 1024) {
        unsigned int w = cmb[e];
        int ni = (int)(w >> 2);
        float2 me = sps[e];
        bool dead, undec;
        SCAN_FLAGS(ni, me, dead, undec);
        if (dead) cmb[e] = (w & ~3u) | ST_D;
        else if (!undec) cmb[e] = (w & ~3u) | ST_A;
        bool pendf = !dead && undec;
        unsigned long long act = __ballot(true);
        unsigned long long bal = __ballot(pendf);
        int leader = __builtin_ctzll(act);
        int cnt = __popcll(bal);
        int wbase = 0;
        if (lane == leader && cnt) wbase = atomicAdd(&pcnt[0], cnt);
        wbase = __shfl(wbase, leader, 64);
        if (pendf) {
            int pos = wbase + __popcll(bal & ((1ull << lane) - 1ull));
            if (pos < PCAP) plist[0][pos] = (unsigned short)e;
        }
    }

    // ---- P4 rounds over compacted pending (proven engine) ----
    int cur = 0;
    for (int round = 0; round < NPTS; ++round) {
        __syncthreads();
        int pc = pcnt[cur];
        if (pc == 0) break;
        if (pc > PCAP) {                        // overflow fallback: full sweeps
            for (;;) {
                bool any = false;
                __syncthreads();
                for (int e = tid; e < M; e += 1024) {
                    unsigned int w = cmb[e];
                    if ((w & 3u) != ST_U) continue;
                    int ni = (int)(w >> 2);
                    float2 me = sps[e];
                    bool dead, undec;
                    SCAN_FLAGS(ni, me, dead, undec);
                    if (dead) cmb[e] = (w & ~3u) | ST_D;
                    else if (!undec) cmb[e] = (w & ~3u) | ST_A;
                    else any = true;
                }
                if (__syncthreads_count(any) == 0) break;
            }
            break;
        }
        if (tid == 0) pcnt[cur ^ 1] = 0;
        __syncthreads();
        for (int idx = tid; idx < pc; idx += 1024) {
            int e = plist[cur][idx];
            unsigned int w = cmb[e];
            int ni = (int)(w >> 2);
            float2 me = sps[e];
            bool dead, undec;
            SCAN_FLAGS(ni, me, dead, undec);
            if (dead) cmb[e] = (w & ~3u) | ST_D;
            else if (!undec) cmb[e] = (w & ~3u) | ST_A;
            bool pendf = !dead && undec;
            unsigned long long act = __ballot(true);
            unsigned long long bal = __ballot(pendf);
            int leader = __builtin_ctzll(act);
            int cnt = __popcll(bal);
            int wbase = 0;
            if (lane == leader && cnt) wbase = atomicAdd(&pcnt[cur ^ 1], cnt);
            wbase = __shfl(wbase, leader, 64);
            if (pendf) {
                int pos = wbase + __popcll(bal & ((1ull << lane) - 1ull));
                if (pos < PCAP) plist[cur ^ 1][pos] = (unsigned short)e;
            }
        }
        cur ^= 1;
    }
    __syncthreads();

    // ---- kept-rank over grid space: ballot bitmask + wave-scanned prefix ----
    for (int k = 0; k < 8; ++k) {
        int e = (k << 10) + tid;
        unsigned long long bal = __ballot((cmb[e] & 3u) == ST_A);  // e>=M stays U
        if (lane == 0) ballots[(k << 4) + wv] = bal;
    }
    __syncthreads();
    if (wv == 0) {
        unsigned int p0 = (unsigned int)__popcll(ballots[2 * lane]);
        unsigned int p1 = (unsigned int)__popcll(ballots[2 * lane + 1]);
        unsigned int s = p0 + p1, v = s;
        for (int d = 1; d < 64; d <<= 1) {
            unsigned int u = __shfl_up(v, d, 64);
            if (lane >= d) v += u;
        }
        base128[2 * lane] = v - s;
        base128[2 * lane + 1] = v - p1;
        if (lane == 63) sK = (int)v;
    }
    __syncthreads();
    #define KRANK(E) ((int)base128[(E) >> 6] +                                    \
                      __popcll(ballots[(E) >> 6] & ((1ull << ((E) & 63)) - 1ull)))
    if (sK > LDSK) {                            // cold fallback prep: zero globals
        for (int k = tid; k < NPTS; k += 1024) {
            sumx[base + k] = 0.f; sumy[base + k] = 0.f; cntw[base + k] = 0.f;
        }
        __syncthreads();
    }

    // ---- P5: assignment + LDS accumulation (contiguous branchless argmin) ----
    #define ROW_ARGMIN(CY, CX0, CX1, ME, BD, BE, BN)                              \
    {                                                                             \
        unsigned int wa = cellpack[(CY) * GRD + (CX0)];                           \
        unsigned int wb = cellpack[(CY) * GRD + (CX1)];                           \
        unsigned int f0 = wa >> 16, f1 = (wb >> 16) + (wb & 0xffffu);             \
        for (unsigned int f = f0; f < f1; ++f) {                                  \
            unsigned int wf = cmb[f];                                             \
            float2 q = sps[f];                                                    \
            float dx = __fsub_rn((ME).x, q.x), dy = __fsub_rn((ME).y, q.y);       \
            float d2 = __fadd_rn(__fmul_rn(dx, dx), __fmul_rn(dy, dy));           \
            int nf = (int)(wf >> 2);                                              \
            bool better = ((wf & 3u) == ST_A) &                                   \
                          ((d2 < BD) | ((d2 == BD) & (nf < BN)));                 \
            BD = better ? d2 : BD;                                                \
            BE = better ? (int)f : BE;                                            \
            BN = better ? nf : BN;                                                \
        }                                                                         \
    }
    for (int e = tid; e < M; e += 1024) {
        unsigned int w = cmb[e];
        float2 me = sps[e];
        int be;
        if ((w & 3u) == ST_A) {
            be = e;                              // self: unique d2 = 0
        } else {
            int cx0 = max(0, (int)((me.x - RAD - bminx) * inv));
            int cx1 = min(GRD - 1, (int)((me.x + RAD - bminx) * inv));
            int cy0 = max(0, (int)((me.y - RAD - bminy) * inv));
            int cy1 = min(GRD - 1, (int)((me.y + RAD - bminy) * inv));
            float bd = 3e38f;
            be = -1;
            int bn = 1 << 30;
            ROW_ARGMIN(cy0, cx0, cx1, me, bd, be, bn);
            if (cy1 > cy0) ROW_ARGMIN(cy1, cx0, cx1, me, bd, be, bn);
            if (be < 0) continue;                // impossible when M > 0
        }
        int r = KRANK(be);
        if (r < LDSK) {
            atomicAdd(&ksx[r], me.x);
            atomicAdd(&ksy[r], me.y);
            atomicAdd(&kcn[r], 1.0f);
        } else {                                 // cold fallback: global by grid pos
            atomicAdd(&sumx[base + be], me.x);
            atomicAdd(&sumy[base + be], me.y);
            atomicAdd(&cntw[base + be], 1.0f);
        }
    }
    __syncthreads();

    // ---- P6: kept candidates overwrite the zeroed output slice ----
    for (int e = tid; e < M; e += 1024) {
        unsigned int w = cmb[e];
        if ((w & 3u) != ST_A) continue;
        int n = (int)(w >> 2);
        int r = KRANK(e);
        float sx, sy, c;
        if (r < LDSK) { sx = ksx[r]; sy = ksy[r]; c = kcn[r]; }
        else { sx = sumx[base + e]; sy = sumy[base + e]; c = cntw[base + e]; }
        out[2 * (base + n)]     = sx / c;        // c >= 1 (self-assign)
        out[2 * (base + n) + 1] = sy / c;
        ok[n] = 1.0f;
    }
}

// ---------------------------------------------------------------------------
extern "C" void kernel_launch(void* const* d_in, const int* in_sizes, int n_in,
                              void* d_out, int out_size, void* d_ws, size_t ws_size,
                              hipStream_t stream) {
    const float* seg   = (const float*)d_in[0];   // [B,C,H,W] f32
    const float* lidar = (const float*)d_in[1];   // [B,2,H,W] f32
    float* out = (float*)d_out;

    const size_t A = (size_t)NP * NPTS;           // 49152
    float* sumx = (float*)d_ws;                   // 4A (fallback only)
    float* sumy = sumx + A;                       // 4A
    float* cntw = sumy + A;                       // 4A

    k_fused<<<NP, 1024, 0, stream>>>(seg, lidar, sumx, sumy, cntw, out);
}